// Round 2
// baseline (270.115 us; speedup 1.0000x reference)
//
#include <hip/hip_runtime.h>

// DVQ bottleneck: B=8, N=4096, D=1024, S=4, K=16, d=256, BETA=0.25
// Outputs (flat fp32 in d_out): z[8*4096*1024], ids_packed[32768] (as float),
// vq_total[1].
//
// R7: kill the address-divergent h loads (R3-R6 all loaded h with lane=token
// -> 4KB lane stride -> 64 cache lines per load instruction; R6's counters:
// FETCH 191MB vs 130MB ideal from line-eviction refetch, all pipes <40%).
// New structure: block = 64 tokens x 1 segment, 4 waves.
//   (a) h staged into a 64KB LDS tile with PERFECTLY COALESCED loads: one
//       token's segment slice is 1KB contiguous -> one wave-instruction
//       (64 lanes x float4) per row. Reg-staged (load->ds_write).
//   (b) XOR swizzle phys_j = j ^ row on the float4 index: the compute read
//       (fixed col, lanes=rows) would otherwise be a 32-way bank conflict;
//       with swizzle both ds_write and ds_read run at the 8-cy floor.
//       (+1 pad impossible: 64*65*16 + 16K > 81920B half-CU budget.)
//   (c) compute identical to R6 numerics (fp64 FMA dots, exact cvt from fp32
//       codebook in LDS, same argmin strict-< tie-break), T=1 token/lane.
//   (d) partial-reduce arena + ids alias the h tile after compute; phase-2
//       z-write reads codebook from LDS (conflict-free) instead of global.
// LDS = 65536 (h) + 16384 (cb) = 81920B exactly -> 2 blocks/CU; resident
// blocks pipeline staging (mem-bound ~5us) against fp64 compute (~2.7us).

#define D_FULL 1024
#define SEG 4
#define DSEG 256
#define KC 16

// Prep (64 blocks x 256): fp64 ||c||^2 per (s,k), zero ids_out + loss
// (d_out/d_ws poisoned 0xAA before every timed launch).
__global__ __launch_bounds__(256) void dvq_prep(const float* __restrict__ cb,
                                                double* __restrict__ c2d,
                                                float* __restrict__ ids_out,
                                                float* __restrict__ loss_out) {
    __shared__ double ws[4];
    const int b = blockIdx.x;    // 0..63 == (s,k) pair
    const int t = threadIdx.x;
    const int lane = t & 63;
    const int w = t >> 6;

    ids_out[b * 512 + t] = 0.0f;
    ids_out[b * 512 + 256 + t] = 0.0f;
    if (b == 0 && t == 0) *loss_out = 0.0f;

    double v = (double)cb[b * 256 + t];
    double sq = v * v;
#pragma unroll
    for (int off = 32; off > 0; off >>= 1)
        sq += __shfl_down(sq, off, 64);
    if (lane == 0) ws[w] = sq;
    __syncthreads();
    if (t == 0) c2d[b] = ws[0] + ws[1] + ws[2] + ws[3];
}

__global__ __launch_bounds__(256) void dvq_main(const float* __restrict__ h,
                                                const float* __restrict__ cb,
                                                const double* __restrict__ c2d,
                                                float* __restrict__ z_out,
                                                float* __restrict__ ids_out,
                                                float* __restrict__ loss_out) {
    // hl: 64KB h tile [64 tokens][64 float4], XOR-swizzled (phys = j ^ tok).
    // After compute it is aliased by the cross-wave partial buffer
    // [3][64][17] doubles = 26112B and ids[64] at byte 26112.
    __shared__ __align__(16) float4 hl[64 * 64];
    __shared__ __align__(16) float cbl[KC * DSEG];  // 16KB fp32 codebook slice

    const int i = threadIdx.x;
    const int lane = i & 63;                           // token within block
    const int w = i >> 6;                              // wave id == d-chunk
    const int ch = __builtin_amdgcn_readfirstlane(w);  // wave-uniform SGPR

    const int s = blockIdx.x & 3;                      // segment
    const long tok_base = (long)(blockIdx.x >> 2) * 64;

    // ---- Stage fp32 codebook slice (16 KB) straight from cb (L2-resident) ----
    {
        const float4* src = reinterpret_cast<const float4*>(cb + s * (KC * DSEG));
        float4* dst = reinterpret_cast<float4*>(cbl);
#pragma unroll
        for (int jj = 0; jj < 4; ++jj)
            dst[jj * 256 + i] = src[jj * 256 + i];
    }

    // ---- Stage h tile: wave = 16 rows, each row one coalesced 1KB load.
    // Swizzled ds_write: value j=lane of row r goes to phys slot (lane ^ r).
    {
#pragma unroll
        for (int half = 0; half < 2; ++half) {
            float4 tmp[8];
#pragma unroll
            for (int rr = 0; rr < 8; ++rr) {
                const int r = ch * 16 + half * 8 + rr;
                tmp[rr] = *(const float4*)(h + (tok_base + r) * D_FULL +
                                           (long)s * DSEG + lane * 4);
            }
#pragma unroll
            for (int rr = 0; rr < 8; ++rr) {
                const int r = ch * 16 + half * 8 + rr;
                hl[r * 64 + (lane ^ r)] = tmp[rr];
            }
        }
    }
    __syncthreads();

    // ---- Phase 1: fp64 partial dots. lane = token, wave = 64-dim chunk.
    // h via swizzled LDS read (bank-floor), codebook via b128 broadcast. ----
    const float* cbs = cbl + ch * 64;  // wave-uniform
    const int tk = lane;

    double dot[KC];
#pragma unroll
    for (int k = 0; k < KC; ++k) dot[k] = 0.0;
    double ze2 = 0.0;

#pragma unroll 4
    for (int j = 0; j < 16; ++j) {
        const int jj = ch * 16 + j;                 // logical float4 col
        float4 z4 = hl[tk * 64 + (jj ^ tk)];        // swizzled read
        double z0 = (double)z4.x, z1 = (double)z4.y;
        double z2 = (double)z4.z, z3 = (double)z4.w;
        ze2 = fma(z0, z0, ze2);
        ze2 = fma(z1, z1, ze2);
        ze2 = fma(z2, z2, ze2);
        ze2 = fma(z3, z3, ze2);
#pragma unroll
        for (int k = 0; k < KC; ++k) {
            float4 c4 = *(const float4*)(cbs + k * DSEG + j * 4);  // broadcast
            double a = dot[k];
            a = fma(z0, (double)c4.x, a);
            a = fma(z1, (double)c4.y, a);
            a = fma(z2, (double)c4.z, a);
            a = fma(z3, (double)c4.w, a);
            dot[k] = a;
        }
    }

    // ---- Cross-wave reduction: partials alias the h tile (reads done) ----
    __syncthreads();  // all waves finished reading hl
    double* part = (double*)hl;                       // [3][64][17]
    int* ids_l = (int*)((char*)hl + 26112);           // [64]
    if (w != 0) {
        double* p = part + ((w - 1) * 64 + lane) * (KC + 1);
#pragma unroll
        for (int k = 0; k < KC; ++k) p[k] = dot[k];
        p[KC] = ze2;
    }
    __syncthreads();

    if (w == 0) {
#pragma unroll
        for (int c = 0; c < 3; ++c) {
            const double* p = part + (c * 64 + lane) * (KC + 1);
#pragma unroll
            for (int k = 0; k < KC; ++k) dot[k] += p[k];
            ze2 += p[KC];
        }

        // argmin; strict < keeps lowest k (jnp.argmin first-index tie-break)
        const double* c2s = c2d + s * KC;  // 128 B, scalar loads
        double best = c2s[0] - 2.0 * dot[0];
        int bk = 0;
#pragma unroll
        for (int k = 1; k < KC; ++k) {
            double sc = c2s[k] - 2.0 * dot[k];
            if (sc < best) { best = sc; bk = k; }
        }
        ids_l[lane] = bk;

        // ids_packed contribution: bk * 16^s, exact in fp32 (<= 61440)
        atomicAdd(&ids_out[tok_base + lane], (float)(bk << (4 * s)));

        // loss: min dist = ||ze||^2 + (||c||^2 - 2 ze.c), reduce 64 tokens
        double mind = ze2 + best;
#pragma unroll
        for (int off = 32; off > 0; off >>= 1)
            mind += __shfl_down(mind, off, 64);
        if (lane == 0)
            atomicAdd(loss_out, (float)(mind * (1.25 / 8388608.0)));
    }
    __syncthreads();  // ids_l visible to all waves

    // ---- Phase 2: z write from LDS codebook, 16 rows/wave, 1KB coalesced ----
    const float4* cbl4 = (const float4*)cbl;
#pragma unroll 4
    for (int r0 = 0; r0 < 16; ++r0) {
        int r = ch * 16 + r0;
        int k = ids_l[r];                      // wave-uniform broadcast
        float4 v = cbl4[k * 64 + lane];        // per-lane consecutive, no conflict
        ((float4*)(z_out + (tok_base + r) * D_FULL + (long)s * DSEG))[lane] = v;
    }
}

extern "C" void kernel_launch(void* const* d_in, const int* in_sizes, int n_in,
                              void* d_out, int out_size, void* d_ws, size_t ws_size,
                              hipStream_t stream) {
    const float* h  = (const float*)d_in[0];
    const float* cb = (const float*)d_in[1];

    const int n_h = in_sizes[0];          // 33554432
    const int tokens = n_h / D_FULL;      // 32768

    float* z_out    = (float*)d_out;
    float* ids_out  = z_out + (size_t)n_h;
    float* loss_out = ids_out + tokens;

    double* c2d = (double*)d_ws;          // 64 doubles

    dvq_prep<<<64, 256, 0, stream>>>(cb, c2d, ids_out, loss_out);
    dvq_main<<<(tokens / 64) * SEG, 256, 0, stream>>>(h, cb, c2d, z_out,
                                                      ids_out, loss_out);
}

// Round 4
// 243.002 us; speedup vs baseline: 1.1116x; 1.1116x over previous
//
#include <hip/hip_runtime.h>

// DVQ bottleneck: B=8, N=4096, D=1024, S=4, K=16, d=256, BETA=0.25
// Outputs (flat fp32 in d_out): z[8*4096*1024], ids_packed[32768] (as float),
// vq_total[1].
//
// R9 = R8 with the staging-coverage bug fixed. R8's concept: R7 fixed traffic
// (FETCH 191->66MB, conflicts 0) but was flat at 116us -- LDS 80KB -> 2
// blocks/CU -> 8 waves/CU (occ 18%), sync reg-staged loads, 4 barriers
// convoying. R8/R9 attack concurrency, keeping R7's tile + XOR swizzle:
//   (a) 512-thread blocks (8 waves), same 64-token x 1-segment tile; per-wave
//       chunk = 32 dims. LDS/block unchanged -> still 2 blocks/CU but now
//       16 waves/CU (2x latency hiding).
//   (b) staging via __builtin_amdgcn_global_load_lds width=16: LDS dest is
//       LINEAR (row*1KB, wave-uniform base), XOR swizzle moved into the
//       per-lane GLOBAL address (lane^r)*16B (guide m173 pattern). One async
//       issue burst, drained once by the barrier; no VGPR round trip.
//   (c) cross-wave partial arena [7][64][17] fp64 = 60928B aliases h tile.
// R8 BUG: cb slice is 16KB = 16 wave-loads, but each wave issued only ONE
// 1KB load at a 2KB stride -> odd kilobytes of the codebook LDS were never
// written (absmax 4.9e14). R9: two loads per wave (half=0,1) cover all 16KB.
// Numerics identical to R5-R7: fp64 dots, exact cvt from fp32 codebook,
// strict-< argmin (jnp first-index tie-break), loss scale 1.25/8388608.

#define D_FULL 1024
#define SEG 4
#define DSEG 256
#define KC 16

#define GLOBAL_AS __attribute__((address_space(1)))
#define LDS_AS __attribute__((address_space(3)))

static __device__ __forceinline__ void load_lds16(const void* g, void* l) {
    __builtin_amdgcn_global_load_lds((GLOBAL_AS const unsigned int*)g,
                                     (LDS_AS unsigned int*)l, 16, 0, 0);
}

// Prep (64 blocks x 256): fp64 ||c||^2 per (s,k), zero ids_out + loss
// (d_out/d_ws poisoned 0xAA before every timed launch).
__global__ __launch_bounds__(256) void dvq_prep(const float* __restrict__ cb,
                                                double* __restrict__ c2d,
                                                float* __restrict__ ids_out,
                                                float* __restrict__ loss_out) {
    __shared__ double ws[4];
    const int b = blockIdx.x;    // 0..63 == (s,k) pair
    const int t = threadIdx.x;
    const int lane = t & 63;
    const int w = t >> 6;

    ids_out[b * 512 + t] = 0.0f;
    ids_out[b * 512 + 256 + t] = 0.0f;
    if (b == 0 && t == 0) *loss_out = 0.0f;

    double v = (double)cb[b * 256 + t];
    double sq = v * v;
#pragma unroll
    for (int off = 32; off > 0; off >>= 1)
        sq += __shfl_down(sq, off, 64);
    if (lane == 0) ws[w] = sq;
    __syncthreads();
    if (t == 0) c2d[b] = ws[0] + ws[1] + ws[2] + ws[3];
}

__global__ __launch_bounds__(512, 4) void dvq_main(const float* __restrict__ h,
                                                   const float* __restrict__ cb,
                                                   const double* __restrict__ c2d,
                                                   float* __restrict__ z_out,
                                                   float* __restrict__ ids_out,
                                                   float* __restrict__ loss_out) {
    // hl: 64KB h tile [64 tokens][64 float4], XOR-swizzled (phys = j ^ tok).
    // After compute it is aliased by the cross-wave partial buffer
    // [7][64][17] doubles = 60928B and ids[64] at byte 60928.
    __shared__ __align__(16) float4 hl[64 * 64];
    __shared__ __align__(16) float cbl[KC * DSEG];  // 16KB fp32 codebook slice

    const int i = threadIdx.x;
    const int lane = i & 63;                           // token within block
    const int w = i >> 6;                              // wave id == d-chunk (0..7)
    const int ch = __builtin_amdgcn_readfirstlane(w);  // wave-uniform SGPR

    const int s = blockIdx.x & 3;                      // segment
    const long tok_base = (long)(blockIdx.x >> 2) * 64;

    char* hl_b = (char*)hl;
    char* cbl_b = (char*)cbl;

    // ---- Async staging burst: 8 h rows + 2 cb KBs per wave, all
    // global_load_lds width=16. LDS dest linear (wave-uniform base + lane*16);
    // XOR swizzle applied to the per-lane GLOBAL source address. ----
#pragma unroll
    for (int rr = 0; rr < 8; ++rr) {
        const int r = ch * 8 + rr;
        load_lds16(h + (tok_base + r) * D_FULL + (long)s * DSEG +
                       ((lane ^ r) << 2),
                   hl_b + r * 1024);
    }
#pragma unroll
    for (int half = 0; half < 2; ++half) {
        // wave ch covers cb slice bytes [ch*2048, ch*2048+2048)
        load_lds16(cb + s * (KC * DSEG) + ch * 512 + half * 256 + lane * 4,
                   cbl_b + ch * 2048 + half * 1024);
    }

    __syncthreads();  // compiler drains vmcnt(0) before s_barrier

    // ---- Phase 1: fp64 partial dots. lane = token, wave = 32-dim chunk.
    // h via swizzled LDS read (bank-floor), codebook via b128 broadcast. ----
    const float* cbs = cbl + ch * 32;  // wave-uniform, dims [ch*32, ch*32+32)
    const int tk = lane;

    double dot[KC];
#pragma unroll
    for (int k = 0; k < KC; ++k) dot[k] = 0.0;
    double ze2 = 0.0;

#pragma unroll
    for (int j = 0; j < 8; ++j) {
        const int jj = ch * 8 + j;                  // logical float4 col
        float4 z4 = hl[tk * 64 + (jj ^ tk)];        // swizzled read
        double z0 = (double)z4.x, z1 = (double)z4.y;
        double z2 = (double)z4.z, z3 = (double)z4.w;
        ze2 = fma(z0, z0, ze2);
        ze2 = fma(z1, z1, ze2);
        ze2 = fma(z2, z2, ze2);
        ze2 = fma(z3, z3, ze2);
#pragma unroll
        for (int k = 0; k < KC; ++k) {
            float4 c4 = *(const float4*)(cbs + k * DSEG + j * 4);  // broadcast
            double a = dot[k];
            a = fma(z0, (double)c4.x, a);
            a = fma(z1, (double)c4.y, a);
            a = fma(z2, (double)c4.z, a);
            a = fma(z3, (double)c4.w, a);
            dot[k] = a;
        }
    }

    // ---- Cross-wave reduction: partials alias the h tile (reads done) ----
    __syncthreads();  // all waves finished reading hl
    double* part = (double*)hl;                       // [7][64][17]
    int* ids_l = (int*)((char*)hl + 60928);           // [64]
    if (w != 0) {
        double* p = part + ((w - 1) * 64 + lane) * (KC + 1);
#pragma unroll
        for (int k = 0; k < KC; ++k) p[k] = dot[k];
        p[KC] = ze2;
    }
    __syncthreads();

    if (w == 0) {
#pragma unroll
        for (int c = 0; c < 7; ++c) {
            const double* p = part + (c * 64 + lane) * (KC + 1);
#pragma unroll
            for (int k = 0; k < KC; ++k) dot[k] += p[k];
            ze2 += p[KC];
        }

        // argmin; strict < keeps lowest k (jnp.argmin first-index tie-break)
        const double* c2s = c2d + s * KC;  // 128 B, scalar loads
        double best = c2s[0] - 2.0 * dot[0];
        int bk = 0;
#pragma unroll
        for (int k = 1; k < KC; ++k) {
            double sc = c2s[k] - 2.0 * dot[k];
            if (sc < best) { best = sc; bk = k; }
        }
        ids_l[lane] = bk;

        // ids_packed contribution: bk * 16^s, exact in fp32 (<= 61440)
        atomicAdd(&ids_out[tok_base + lane], (float)(bk << (4 * s)));

        // loss: min dist = ||ze||^2 + (||c||^2 - 2 ze.c), reduce 64 tokens
        double mind = ze2 + best;
#pragma unroll
        for (int off = 32; off > 0; off >>= 1)
            mind += __shfl_down(mind, off, 64);
        if (lane == 0)
            atomicAdd(loss_out, (float)(mind * (1.25 / 8388608.0)));
    }
    __syncthreads();  // ids_l visible to all waves

    // ---- Phase 2: z write from LDS codebook, 8 rows/wave, 1KB coalesced ----
    const float4* cbl4 = (const float4*)cbl;
#pragma unroll
    for (int r0 = 0; r0 < 8; ++r0) {
        int r = ch * 8 + r0;
        int k = ids_l[r];                      // wave-uniform broadcast
        float4 v = cbl4[k * 64 + lane];        // per-lane consecutive, no conflict
        ((float4*)(z_out + (tok_base + r) * D_FULL + (long)s * DSEG))[lane] = v;
    }
}

extern "C" void kernel_launch(void* const* d_in, const int* in_sizes, int n_in,
                              void* d_out, int out_size, void* d_ws, size_t ws_size,
                              hipStream_t stream) {
    const float* h  = (const float*)d_in[0];
    const float* cb = (const float*)d_in[1];

    const int n_h = in_sizes[0];          // 33554432
    const int tokens = n_h / D_FULL;      // 32768

    float* z_out    = (float*)d_out;
    float* ids_out  = z_out + (size_t)n_h;
    float* loss_out = ids_out + tokens;

    double* c2d = (double*)d_ws;          // 64 doubles

    dvq_prep<<<64, 256, 0, stream>>>(cb, c2d, ids_out, loss_out);
    dvq_main<<<(tokens / 64) * SEG, 512, 0, stream>>>(h, cb, c2d, z_out,
                                                      ids_out, loss_out);
}